// Round 5
// baseline (294.383 us; speedup 1.0000x reference)
//
#include <hip/hip_runtime.h>
#include <hip/hip_fp16.h>

// NeuronToSpatialGrid: out[b,e,p] = (sum_n w F[b,n,e]) / (sum_n w + 1e-8),
//   w = exp(-50 dx^2) * exp(-50 dy^2)  (separable).
// R5: block 64m x 128e, grid 512 (2/CU). 4 waves = 2 K-groups x 2 e-halves.
// Wave tile m=64 (4 A-frags, ex*ey in regs) x n=64 (4 B-frags) -> B-frag LDS
// reads amortized 4x over m, pk_mul amortized 4x over n. BK=64, frag-ordered
// conflict-free LDS double-buffer, 1 barrier per 32 MFMAs/wave, K-split
// combined via LDS epilogue reduction.

typedef __attribute__((ext_vector_type(8))) _Float16 half8;
typedef __attribute__((ext_vector_type(2))) _Float16 half2v;
typedef __attribute__((ext_vector_type(4))) float floatx4;

#define NB 4
#define NN 4096
#define NE 256
#define NP 4096

#if defined(__has_builtin)
#if __has_builtin(__builtin_amdgcn_fdot2)
#define HAVE_FDOT2 1
#endif
#endif

__device__ inline float sum8(half8 v, float s) {
#ifdef HAVE_FDOT2
    half2v one; one[0] = (_Float16)1.0f; one[1] = (_Float16)1.0f;
    half2v* p = (half2v*)&v;
#pragma unroll
    for (int j = 0; j < 4; j++) s = __builtin_amdgcn_fdot2(p[j], one, s, false);
#else
#pragma unroll
    for (int j = 0; j < 8; j++) s += (float)v[j];
#endif
    return s;
}

#define MFMA16(a, bb, c) __builtin_amdgcn_mfma_f32_16x16x32_f16(a, bb, c, 0, 0, 0)

// ---------- aux kernel: [0,1024) transpose F->FT,  [1024,1536) EY table ----------
// FT[b][e][n] f16.  EYf[b][ko 512][g4 4][fr 16][j 8] = exp(-50*((g4*16+fr)/63 - y_{ko*8+j})^2)
__global__ __launch_bounds__(256) void aux_kernel(const float* __restrict__ in,
                                                  const float* __restrict__ pos,
                                                  __half* __restrict__ ft,
                                                  __half* __restrict__ EYf) {
    __shared__ float tile[128][33];
    const int bid = blockIdx.x;
    const int tid = threadIdx.x;
    if (bid < 1024) {
        const int nb = bid & 31, eb = (bid >> 5) & 7, b = bid >> 8;
        const int n0 = nb * 128, e0 = eb * 32;
        const int rn = tid >> 3, re = (tid & 7) * 4;
#pragma unroll
        for (int p = 0; p < 4; p++) {
            const int n = p * 32 + rn;
            float4 v = *(const float4*)&in[(size_t)(b * NN + n0 + n) * NE + e0 + re];
            tile[n][re] = v.x; tile[n][re + 1] = v.y; tile[n][re + 2] = v.z; tile[n][re + 3] = v.w;
        }
        __syncthreads();
        const int we = tid >> 6, wn = (tid & 63) * 2;
#pragma unroll
        for (int p = 0; p < 8; p++) {
            const int e = p * 4 + we;
            __half2 h = __floats2half2_rn(tile[wn][e], tile[wn + 1][e]);
            *(__half2*)&ft[(size_t)(b * NE + e0 + e) * NN + n0 + wn] = h;
        }
    } else {
        const int idx = (bid - 1024) * 256 + tid;     // one 8-elem chunk per thread
        const int fr = idx & 15;
        const int g4 = (idx >> 4) & 3;
        const int ko = (idx >> 6) & 511;
        const int b  = idx >> 15;
        const float gy = (float)(g4 * 16 + fr) * (1.0f / 63.0f);
        const float* pb = pos + (size_t)b * NN * 2;
        half8 h;
#pragma unroll
        for (int j = 0; j < 8; j++) {
            const float y = pb[(ko * 8 + j) * 2 + 1];
            const float d = gy - y;
            h[j] = (_Float16)__expf(d * d * -50.0f);
        }
        *(half8*)(EYf + (size_t)idx * 8) = h;
    }
}

// ---------- main fused GEMM ----------
// grid 512: xcd=bid&7 -> (b, et e-half);  mt=bid>>3 -> gx.  Block 64gy x 128e.
// Waves: kg=wave>>1 (K half: kg*2048), ni=wave&1 (e-half of 64).
__global__ __launch_bounds__(256, 2) void nw_gemm(const __half* __restrict__ FT,   // [B][E][N]
                                                  const __half* __restrict__ EYf,  // frag order
                                                  const float* __restrict__ pos,   // [B][N][2]
                                                  float* __restrict__ out) {       // [B][E][P]
    __shared__ __half Bt_s[2][16384];     // 2 x 32 KB: frag-ordered B tiles (2kg x 2c x 8et x 1KB chunks)
    __shared__ __half ex_s[NN];           // 8 KB
    __shared__ float Spart[2][64];

    const int bid = blockIdx.x;
    const int xcd = bid & 7;
    const int b   = xcd >> 1;
    const int et  = xcd & 1;
    const int mt  = bid >> 3;             // gx index
    const int m0  = mt * 64;
    const int e0  = et * 128;
    const int tid = threadIdx.x;

    // --- ex_s: 4096 exps once per block ---
    {
        const float gxv = (float)mt * (1.0f / 63.0f);
        const float2* pg = (const float2*)(pos + (size_t)b * NN * 2);
        for (int i = tid; i < NN; i += 256) {
            float d = gxv - pg[i].x;
            ex_s[i] = __float2half_rn(__expf(d * d * -50.0f));
        }
    }

    // --- staging ids: tid = eh*64 + quad_s*16 + fr_s ---
    const int fr_s = tid & 15, quad_s = (tid >> 4) & 3, eh_s = tid >> 6;
    // q in 0..7: kg=q>>2, c=(q>>1)&1, AB=q&1 (e-row offset 0 / +64 rows)
    const __half* pA = FT + ((size_t)b * NE + e0 + eh_s * 16 + fr_s) * NN + quad_s * 8;
    const __half* pB = pA + (size_t)64 * NN;
    // k offset per q (excluding ss*64): kg*2048 + c*32
    int koff[4];
#pragma unroll
    for (int i = 0; i < 4; i++) koff[i] = (i >> 1) * 2048 + (i & 1) * 32;

    // --- wave ids ---
    const int wave = tid >> 6, lane = tid & 63;
    const int kg = wave >> 1;             // K half
    const int ni = wave & 1;              // e half (64)
    const int fr = lane & 15, quad = lane >> 4;
    const int quad8 = quad * 8;
    const int kbase = kg * 2048;

    const __half* eyp = EYf + ((size_t)b << 18) + fr * 8;
    const int ko_b = kg * 256;            // k-oct base for this K half

    floatx4 acc[4][4] = {};               // [h gy-frag][jj e-frag]
    float s0 = 0.f, s1 = 0.f;             // partial sums: rows (ni*2+0)*16.., (ni*2+1)*16..

    // --- prologue: tile0 -> buf0; tile1 -> regs; ey(ss=0) and ey(ss=1) ---
    uint4 bv[8];
#pragma unroll
    for (int q = 0; q < 8; q++) {
        const __half* p = (q & 1) ? pB : pA;
        bv[q] = *(const uint4*)(p + koff[q >> 1]);
    }
#pragma unroll
    for (int q = 0; q < 8; q++)
        *(uint4*)((char*)&Bt_s[0][0] + q * 4096 + tid * 16) = bv[q];
#pragma unroll
    for (int q = 0; q < 8; q++) {
        const __half* p = (q & 1) ? pB : pA;
        bv[q] = *(const uint4*)(p + koff[q >> 1] + 64);
    }
    half8 eyc[4][2], eyn[4][2];
#pragma unroll
    for (int h = 0; h < 4; h++) {
        eyc[h][0] = *(const half8*)(eyp + (size_t)((ko_b + 0 + quad) * 4 + h) * 128);
        eyc[h][1] = *(const half8*)(eyp + (size_t)((ko_b + 4 + quad) * 4 + h) * 128);
        eyn[h][0] = *(const half8*)(eyp + (size_t)((ko_b + 8 + quad) * 4 + h) * 128);
        eyn[h][1] = *(const half8*)(eyp + (size_t)((ko_b + 12 + quad) * 4 + h) * 128);
    }

    for (int ss = 0; ss < 32; ss++) {
        const int cb = ss & 1;
        __syncthreads();                  // buf[cb] ready; buf[cb^1] readers done
        // stage tile(ss+1) -> buf[cb^1]
        char* wb = (char*)&Bt_s[cb ^ 1][0];
#pragma unroll
        for (int q = 0; q < 8; q++) *(uint4*)(wb + q * 4096 + tid * 16) = bv[q];
        // prefetch tile(ss+2)
        {
            const int kn = ((ss + 2) & 31) * 64;
#pragma unroll
            for (int q = 0; q < 8; q++) {
                const __half* p = (q & 1) ? pB : pA;
                bv[q] = *(const uint4*)(p + koff[q >> 1] + kn);
            }
        }
        // compute: 2 k-chunks x (4 A-frags x 4 B-frags)
#pragma unroll
        for (int c = 0; c < 2; c++) {
            half8 ex8 = *(const half8*)(&ex_s[kbase + ss * 64 + c * 32 + quad8]);
            half8 af0 = ex8 * eyc[0][c];
            half8 af1 = ex8 * eyc[1][c];
            half8 af2 = ex8 * eyc[2][c];
            half8 af3 = ex8 * eyc[3][c];
            if (ni == 0) { s0 = sum8(af0, s0); s1 = sum8(af1, s1); }
            else         { s0 = sum8(af2, s0); s1 = sum8(af3, s1); }
#pragma unroll
            for (int jj = 0; jj < 4; jj++) {
                half8 bf = *(const half8*)(&Bt_s[cb][(size_t)(kg * 1024 + c * 512 + (ni * 4 + jj) * 64 + lane) * 8]);
                acc[0][jj] = MFMA16(af0, bf, acc[0][jj]);
                acc[1][jj] = MFMA16(af1, bf, acc[1][jj]);
                acc[2][jj] = MFMA16(af2, bf, acc[2][jj]);
                acc[3][jj] = MFMA16(af3, bf, acc[3][jj]);
            }
        }
        // rotate ey and prefetch ey(ss+2)
        {
            const int ko2 = ko_b + ((ss + 2) & 31) * 8;
#pragma unroll
            for (int h = 0; h < 4; h++) {
                eyc[h][0] = eyn[h][0];
                eyc[h][1] = eyn[h][1];
                eyn[h][0] = *(const half8*)(eyp + (size_t)((ko2 + 0 + quad) * 4 + h) * 128);
                eyn[h][1] = *(const half8*)(eyp + (size_t)((ko2 + 4 + quad) * 4 + h) * 128);
            }
        }
    }

    __syncthreads();                      // all Bt_s reads done -> reuse as dump

    // --- partial row sums -> Spart[kg][row] (rows ni*32 + {0..31}) ---
    s0 += __shfl_xor(s0, 16, 64); s0 += __shfl_xor(s0, 32, 64);
    s1 += __shfl_xor(s1, 16, 64); s1 += __shfl_xor(s1, 32, 64);
    if (quad == 0) {
        Spart[kg][ni * 32 + fr]      = s0;
        Spart[kg][ni * 32 + 16 + fr] = s1;
    }
    // --- kg=1 dumps acc to LDS ---
    float* dump = (float*)&Bt_s[0][0];    // 32 KB region
    if (kg == 1) {
#pragma unroll
        for (int h = 0; h < 4; h++)
#pragma unroll
            for (int jj = 0; jj < 4; jj++)
                *(floatx4*)&dump[(size_t)(((ni * 4 + h) * 4 + jj) * 64 + lane) * 4] = acc[h][jj];
    }
    __syncthreads();

    // --- kg=0 combines, normalizes, stores ---
    if (kg == 0) {
        float* outb = out + (size_t)b * NE * NP;
#pragma unroll
        for (int h = 0; h < 4; h++) {
            const int rb = h * 16 + quad * 4;
            floatx4 sa = *(const floatx4*)&Spart[0][rb];
            floatx4 sb = *(const floatx4*)&Spart[1][rb];
            floatx4 sv;
            sv.x = 1.0f / (sa.x + sb.x + 1e-8f);
            sv.y = 1.0f / (sa.y + sb.y + 1e-8f);
            sv.z = 1.0f / (sa.z + sb.z + 1e-8f);
            sv.w = 1.0f / (sa.w + sb.w + 1e-8f);
#pragma unroll
            for (int jj = 0; jj < 4; jj++) {
                floatx4 d = *(const floatx4*)&dump[(size_t)(((ni * 4 + h) * 4 + jj) * 64 + lane) * 4];
                floatx4 o = acc[h][jj];
                o.x = (o.x + d.x) * sv.x;
                o.y = (o.y + d.y) * sv.y;
                o.z = (o.z + d.z) * sv.z;
                o.w = (o.w + d.w) * sv.w;
                const int e = e0 + ni * 64 + jj * 16 + fr;
                *(floatx4*)&outb[(size_t)e * NP + m0 + rb] = o;
            }
        }
    }
}

extern "C" void kernel_launch(void* const* d_in, const int* in_sizes, int n_in,
                              void* d_out, int out_size, void* d_ws, size_t ws_size,
                              hipStream_t stream) {
    const float* feat = (const float*)d_in[0];   // [4][4096][256] f32
    const float* pos  = (const float*)d_in[1];   // [4][4096][2]  f32
    float* out = (float*)d_out;                  // [4][256][4096] f32
    __half* FT  = (__half*)d_ws;                                        // 8.39 MB
    __half* EYf = (__half*)((char*)d_ws + (size_t)NB * NE * NN * 2);    // +2.10 MB

    hipLaunchKernelGGL(aux_kernel, dim3(1536), dim3(256), 0, stream, feat, pos, FT, EYf);
    hipLaunchKernelGGL(nw_gemm, dim3(512), dim3(256), 0, stream, FT, EYf, pos, out);
}

// Round 6
// 158.423 us; speedup vs baseline: 1.8582x; 1.8582x over previous
//
#include <hip/hip_runtime.h>
#include <hip/hip_fp16.h>

// NeuronToSpatialGrid: out[b,e,p] = (sum_n w F[b,n,e]) / (sum_n w + 1e-8),
//   w = exp(-50 dx^2) * exp(-50 dy^2) (separable).
// R6: grid 512 = 64mt x 4b x 2kg (K-split 2048), 2 blocks/CU. 256 thr, 4 waves
// = 4 e-groups; wave tile 64m x 64e (acc = 64 VGPR, counted!). A = ex (LDS
// broadcast) * ey (LDS, staged per BK=128 -> 1 barrier / 4 substeps). B direct
// from global in MFMA-frag order (no LDS, slice read once per block). Partials
// (f16) + partial sums to ws; combine kernel normalizes.

typedef __attribute__((ext_vector_type(8))) _Float16 half8;
typedef __attribute__((ext_vector_type(2))) _Float16 half2v;
typedef __attribute__((ext_vector_type(4))) float floatx4;

#define NB 4
#define NN 4096
#define NE 256
#define NP 4096

#if defined(__has_builtin)
#if __has_builtin(__builtin_amdgcn_fdot2)
#define HAVE_FDOT2 1
#endif
#endif

__device__ inline float sum8(half8 v, float s) {
#ifdef HAVE_FDOT2
    half2v one; one[0] = (_Float16)1.0f; one[1] = (_Float16)1.0f;
    half2v* p = (half2v*)&v;
#pragma unroll
    for (int j = 0; j < 4; j++) s = __builtin_amdgcn_fdot2(p[j], one, s, false);
#else
#pragma unroll
    for (int j = 0; j < 8; j++) s += (float)v[j];
#endif
    return s;
}

#define MFMA16(a, bb, c) __builtin_amdgcn_mfma_f32_16x16x32_f16(a, bb, c, 0, 0, 0)

// ---------------- aux kernel ----------------
// bid < 1024: F[b][n][e] f32 -> FTf in B-frag chunk order:
//   chunk (b, kc 128, ec 16, quad 4, fr 16) of 8 halves; value F[e=ec*16+fr][k=kc*32+quad*8+j].
// bid >= 1024 (512 blocks): EYf in A-frag chunk order:
//   chunk (b, kb 32, c 4, h 4, quad 4, fr 16); value exp(-50*((h*16+fr)/63 - y_k)^2), k=(kb*4+c)*32+quad*8+j.
__global__ __launch_bounds__(256) void aux_kernel(const float* __restrict__ in,
                                                  const float* __restrict__ pos,
                                                  __half* __restrict__ ftf,
                                                  __half* __restrict__ eyf) {
    const int bid = blockIdx.x;
    const int tid = threadIdx.x;
    if (bid < 1024) {
        __shared__ float tile[128][33];
        const int nb = bid & 31, eb = (bid >> 5) & 7, b = bid >> 8;
        const int n0 = nb * 128, e0 = eb * 32;
        const int rn = tid >> 3, re = (tid & 7) * 4;
#pragma unroll
        for (int p = 0; p < 4; p++) {
            const int n = p * 32 + rn;
            float4 v = *(const float4*)&in[(size_t)(b * NN + n0 + n) * NE + e0 + re];
            tile[n][re] = v.x; tile[n][re + 1] = v.y; tile[n][re + 2] = v.z; tile[n][re + 3] = v.w;
        }
        __syncthreads();
        const int kc_l = tid >> 6, quad = (tid >> 4) & 3, fr = tid & 15;
#pragma unroll
        for (int ec_l = 0; ec_l < 2; ec_l++) {
            half8 h;
#pragma unroll
            for (int j = 0; j < 8; j++)
                h[j] = (_Float16)tile[kc_l * 32 + quad * 8 + j][ec_l * 16 + fr];
            const size_t chunk = (((size_t)(b * 128 + nb * 4 + kc_l) * 16 + (eb * 2 + ec_l)) * 4 + quad) * 16 + fr;
            *(half8*)(ftf + chunk * 8) = h;
        }
    } else {
        const int idx = (bid - 1024) * 256 + tid;           // [0, 131072)
        const int fr = idx & 15;
        const int quad = (idx >> 4) & 3;
        const int h4 = (idx >> 6) & 3;
        const int c = (idx >> 8) & 3;
        const int kb = (idx >> 10) & 31;
        const int b = idx >> 15;
        const float gy = (float)(h4 * 16 + fr) * (1.0f / 63.0f);
        const int k0 = (kb * 4 + c) * 32 + quad * 8;
        const float* pb = pos + (size_t)b * NN * 2;
        half8 h;
#pragma unroll
        for (int j = 0; j < 8; j++) {
            const float d = gy - pb[(k0 + j) * 2 + 1];
            h[j] = (_Float16)__expf(d * d * -50.0f);
        }
        *(half8*)(eyf + (size_t)idx * 8) = h;
    }
}

// ---------------- main fused GEMM (partials) ----------------
// grid 512: kg=bid&1, b=(bid>>1)&3 (xcd pin = bid&7), mt=bid>>3. 256 thr.
// 4 waves = e-groups of 64; wave tile 64m x 64e, K = 2048 (kg half).
__global__ __launch_bounds__(256, 2) void nw_gemm(const __half* __restrict__ FTf,
                                                  const __half* __restrict__ EYf,
                                                  const float* __restrict__ pos,
                                                  __half* __restrict__ Pw,       // [kg][b][mt][gy64][e256] f16
                                                  float* __restrict__ Sp) {      // [kg][b][4096] f32
    __shared__ __half EYs[2][8192];       // 2 x 16 KB: A-frag-ordered ey, BK=128
    __shared__ __half ex_s[NN];           // 8 KB

    const int bid = blockIdx.x;
    const int kg = bid & 1;
    const int b  = (bid >> 1) & 3;
    const int mt = bid >> 3;
    const int tid = threadIdx.x;

    // ex_s once per block (gx = mt constant)
    {
        const float gxv = (float)mt * (1.0f / 63.0f);
        const float2* pg = (const float2*)(pos + (size_t)b * NN * 2);
        for (int i = tid; i < NN; i += 256) {
            float d = gxv - pg[i].x;
            ex_s[i] = __float2half_rn(__expf(d * d * -50.0f));
        }
    }

    const int wave = tid >> 6, lane = tid & 63;
    const int eg = wave;                  // e-group of 64
    const int fr = lane & 15, quad = lane >> 4;

    // B source: frag chunks (kc = kg*64 + ss, ec = eg*4 + jj), 1 KB each, lane-contiguous
    const char* bbase = (const char*)FTf +
        (((size_t)(b * 128 + kg * 64) * 16 + eg * 4) << 10) + lane * 16;
    // ey source: 16 KB outer chunks kb = kg*16 + o
    const char* esrc = (const char*)EYf + ((size_t)(b * 32 + kg * 16) << 14) + tid * 64;

    floatx4 acc[4][4] = {};               // [h gy-frag][jj e-frag]
    float s = 0.f;                        // partial row sums for h == eg

    // prologue: EYs[0] <- chunk 0; er <- chunk 1; bf[0] <- ss=0
    uint4 er[4];
#pragma unroll
    for (int q = 0; q < 4; q++) er[q] = *(const uint4*)(esrc + q * 16);
    {
        uint4* d = (uint4*)&EYs[0][0] + tid * 4;
#pragma unroll
        for (int q = 0; q < 4; q++) d[q] = er[q];
    }
#pragma unroll
    for (int q = 0; q < 4; q++) er[q] = *(const uint4*)(esrc + 16384 + q * 16);

    uint4 bf[2][4];
#pragma unroll
    for (int jj = 0; jj < 4; jj++) bf[0][jj] = *(const uint4*)(bbase + jj * 1024);

    __syncthreads();                      // EYs[0] + ex_s ready

    for (int o = 0; o < 16; o++) {
        const int buf = o & 1;
        const char* ebase = (const char*)&EYs[buf][0] + lane * 16;
#pragma unroll
        for (int c = 0; c < 4; c++) {
            const int ss = o * 4 + c;
            // prefetch B for next substep (parity ping-pong)
            const int nss = (ss + 1) & 63;
            const char* pn = bbase + (size_t)nss * 16384;
#pragma unroll
            for (int jj = 0; jj < 4; jj++)
                bf[(c & 1) ^ 1][jj] = *(const uint4*)(pn + jj * 1024);
            // A-frags: ex (broadcast) * ey (LDS, lane-contiguous)
            half8 ex8 = *(const half8*)(&ex_s[kg * 2048 + ss * 32 + quad * 8]);
            half8 af0 = ex8 * *(const half8*)(ebase + (c * 4 + 0) * 1024);
            half8 af1 = ex8 * *(const half8*)(ebase + (c * 4 + 1) * 1024);
            half8 af2 = ex8 * *(const half8*)(ebase + (c * 4 + 2) * 1024);
            half8 af3 = ex8 * *(const half8*)(ebase + (c * 4 + 3) * 1024);
            s = sum8(eg == 0 ? af0 : eg == 1 ? af1 : eg == 2 ? af2 : af3, s);
#pragma unroll
            for (int jj = 0; jj < 4; jj++) {
                half8 bv = *(const half8*)&bf[c & 1][jj];
                acc[0][jj] = MFMA16(af0, bv, acc[0][jj]);
                acc[1][jj] = MFMA16(af1, bv, acc[1][jj]);
                acc[2][jj] = MFMA16(af2, bv, acc[2][jj]);
                acc[3][jj] = MFMA16(af3, bv, acc[3][jj]);
            }
        }
        // write er (chunk o+1) -> EYs[buf^1]; prefetch chunk o+2
        {
            uint4* d = (uint4*)&EYs[buf ^ 1][0] + tid * 4;
#pragma unroll
            for (int q = 0; q < 4; q++) d[q] = er[q];
            const int on = (o + 2 > 15) ? 15 : o + 2;
            const char* ps = esrc + ((size_t)on << 14);
#pragma unroll
            for (int q = 0; q < 4; q++) er[q] = *(const uint4*)(ps + q * 16);
        }
        __syncthreads();
    }

    // partial row sums: reduce over quad; rows gy = eg*16 + fr
    s += __shfl_xor(s, 16, 64);
    s += __shfl_xor(s, 32, 64);
    if (quad == 0)
        Sp[(size_t)(kg * 4 + b) * NP + mt * 64 + eg * 16 + fr] = s;

    // partial accumulators -> Pw f16 [kg][b][mt][gy][e]
    __half* pwb = Pw + ((size_t)((kg * 4 + b) * 64 + mt) << 14);   // 64*256 = 16384
#pragma unroll
    for (int h = 0; h < 4; h++) {
#pragma unroll
        for (int jj = 0; jj < 4; jj++) {
            const int e = eg * 64 + jj * 16 + fr;
#pragma unroll
            for (int r = 0; r < 4; r++) {
                const int gy = h * 16 + quad * 4 + r;
                pwb[gy * 256 + e] = __float2half(acc[h][jj][r]);
            }
        }
    }
}

// ---------------- combine: out = (P0+P1) / (S0+S1+eps) ----------------
// grid 256 = (b 4) x (mt 64); thread t = e.
__global__ __launch_bounds__(256) void combine_kernel(const __half* __restrict__ Pw,
                                                      const float* __restrict__ Sp,
                                                      float* __restrict__ out) {
    __shared__ float rinv[64];
    const int bid = blockIdx.x;
    const int b = bid >> 6, mt = bid & 63;
    const int t = threadIdx.x;
    if (t < 64) {
        const float s = Sp[(size_t)b * NP + mt * 64 + t] +
                        Sp[(size_t)(4 + b) * NP + mt * 64 + t];
        rinv[t] = 1.0f / (s + 1e-8f);
    }
    __syncthreads();
    const __half* p0 = Pw + ((size_t)(b * 64 + mt) << 14);
    const __half* p1 = Pw + ((size_t)((4 + b) * 64 + mt) << 14);
    float* o = out + ((size_t)(b * NE + t)) * NP + mt * 64;
#pragma unroll 4
    for (int gc = 0; gc < 16; gc++) {
        float4 w;
        float* wp = (float*)&w;
#pragma unroll
        for (int r = 0; r < 4; r++) {
            const int gy = gc * 4 + r;
            const float v = __half2float(p0[gy * 256 + t]) + __half2float(p1[gy * 256 + t]);
            wp[r] = v * rinv[gy];
        }
        *(float4*)(o + gc * 4) = w;
    }
}

extern "C" void kernel_launch(void* const* d_in, const int* in_sizes, int n_in,
                              void* d_out, int out_size, void* d_ws, size_t ws_size,
                              hipStream_t stream) {
    const float* feat = (const float*)d_in[0];   // [4][4096][256] f32
    const float* pos  = (const float*)d_in[1];   // [4][4096][2]  f32
    float* out = (float*)d_out;                  // [4][256][4096] f32

    char* ws = (char*)d_ws;
    __half* FTf = (__half*)ws;                               // 8,388,608 B
    __half* EYf = (__half*)(ws + 8388608);                   // 2,097,152 B
    __half* Pw  = (__half*)(ws + 10485760);                  // 16,777,216 B
    float*  Sp  = (float*)(ws + 27262976);                   // 131,072 B   (total ~27.4 MB)

    hipLaunchKernelGGL(aux_kernel, dim3(1536), dim3(256), 0, stream, feat, pos, FTf, EYf);
    hipLaunchKernelGGL(nw_gemm, dim3(512), dim3(256), 0, stream, FTf, EYf, pos, Pw, Sp);
    hipLaunchKernelGGL(combine_kernel, dim3(256), dim3(256), 0, stream, Pw, Sp, out);
}